// Round 6
// baseline (110.037 us; speedup 1.0000x reference)
//
#include <hip/hip_runtime.h>

#define BIGV 1e9f
#define NPT 256            // N == M == 256

// band: |i-j| <= 51.  i-window on diagonal s:
__device__ __forceinline__ int imin_of(int s){
    int a = s - 255; if (a < 0) a = 0;            // j = s-i <= 255
    int c = s - 50;  c = (c > 0) ? (c >> 1) : 0;  // ceil((s-51)/2)
    return (a > c) ? a : c;
}
__device__ __forceinline__ int imax_of(int s){
    int a = (s < 255) ? s : 255;
    int c = (s + 51) >> 1;                        // floor((s+51)/2)
    return (a < c) ? a : c;
}

// wave-wide shift by 1 with BIG fill (no LDS): lane l <- x[l-1]
__device__ __forceinline__ float dpp_shr1(float x){
    return __int_as_float(__builtin_amdgcn_update_dpp(
        __float_as_int(BIGV), __float_as_int(x), 0x138 /*WAVE_SHR1*/, 0xF, 0xF, false));
}
__device__ __forceinline__ float dpp_shl1(float x){
    return __int_as_float(__builtin_amdgcn_update_dpp(
        __float_as_int(BIGV), __float_as_int(x), 0x130 /*WAVE_SHL1*/, 0xF, 0xF, false));
}

__device__ __forceinline__ float min3f(float a, float b, float c){
    float r;
    asm("v_min3_f32 %0, %1, %2, %3" : "=v"(r) : "v"(a), "v"(b), "v"(c));
    return r;
}

// ---------------- Kernel A: banded distances -> full f32 rows in d_ws ------------
// Df layout: f32, row (b*512 + s) has 256 floats (i = 0..255), BIG outside band.
// Row 511 all-BIG. grid = B*8, block (b,c) owns s in [64c, 64c+63].
__global__ __launch_bounds__(256) void ldtw_dist(const float* __restrict__ X,
                                                 const float* __restrict__ Y,
                                                 float* __restrict__ Df)
{
    __shared__ float4 Xs[96*17];
    __shared__ float4 Ys[96*17];
    __shared__ float nX[96], nY[96];
    __shared__ float Band[64*65];   // pitch 65
    const int b  = blockIdx.x >> 3;
    const int c  = blockIdx.x & 7;
    const int s0 = c << 6;
    const int s1 = (s0 + 63 > 510) ? 510 : (s0 + 63);
    const int ilo = imin_of(s0), ihi = imax_of(s1);
    const int jlo = s0 - imax_of(s0), jhi = s1 - imin_of(s1);
    const int nx = ihi - ilo + 1, ny = jhi - jlo + 1;   // each <= 96
    const int t = threadIdx.x;
    const float4* Xb = (const float4*)(X + (size_t)b * NPT * 64);
    const float4* Yb = (const float4*)(Y + (size_t)b * NPT * 64);

    for (int idx = t; idx < nx * 16; idx += 256){
        int r = idx >> 4, k = idx & 15;
        Xs[r*17 + k] = Xb[(ilo + r)*16 + k];
    }
    for (int idx = t; idx < ny * 16; idx += 256){
        int r = idx >> 4, k = idx & 15;
        Ys[r*17 + k] = Yb[(jlo + r)*16 + k];
    }
    __syncthreads();

    for (int r = t; r < nx + ny; r += 256){
        const float4* row = (r < nx) ? (Xs + r*17) : (Ys + (r - nx)*17);
        float acc = 0.f;
        #pragma unroll
        for (int k = 0; k < 16; ++k){
            float4 v = row[k];
            acc += v.x*v.x + v.y*v.y + v.z*v.z + v.w*v.w;
        }
        if (r < nx) nX[r] = acc; else nY[r - nx] = acc;
    }
    __syncthreads();

    // phase 1: 6x6 register-tiled dot products over the covering rectangle.
    // Thread (ti,tj) owns rows {ti+16u} x cols {tj+16v}, u,v in [0,6).
    // Out-of-band cells are computed and discarded (validity-guarded write).
    {
        const int ti = t >> 4;       // 0..15
        const int tj = t & 15;       // 0..15
        float acc[6][6];
        #pragma unroll
        for (int u = 0; u < 6; ++u)
            #pragma unroll
            for (int v = 0; v < 6; ++v) acc[u][v] = 0.f;

        #pragma unroll
        for (int k = 0; k < 16; ++k){
            float4 xa[6], ya[6];
            #pragma unroll
            for (int u = 0; u < 6; ++u){
                xa[u] = Xs[(ti + u*16)*17 + k];
                ya[u] = Ys[(tj + u*16)*17 + k];
            }
            #pragma unroll
            for (int u = 0; u < 6; ++u)
                #pragma unroll
                for (int v = 0; v < 6; ++v)
                    acc[u][v] += xa[u].x*ya[v].x + xa[u].y*ya[v].y
                               + xa[u].z*ya[v].z + xa[u].w*ya[v].w;
        }

        #pragma unroll
        for (int u = 0; u < 6; ++u){
            #pragma unroll
            for (int v = 0; v < 6; ++v){
                const int iloc = ti + u*16, jloc = tj + v*16;
                const int i = ilo + iloc, j = jlo + jloc;
                const int s = i + j;
                if (s >= s0 && s <= s1){
                    const int im = imin_of(s), ix = imax_of(s);
                    if (i >= im && i <= ix)
                        Band[(s - s0)*65 + (i - im)] =
                            nX[iloc] + nY[jloc] - 2.f*acc[u][v];
                }
            }
        }
    }
    __syncthreads();

    // phase 2: emit full 256-wide f32 rows (BIG outside band), coalesced float4
    float4* Df4 = (float4*)Df;
    const size_t rowbase4 = ((size_t)(b * 512 + s0)) << 6;   // float4 units, 64/row
    for (int slot = t; slot < 64*64; slot += 256){
        const int sd = slot >> 6, q = slot & 63;
        const int s  = s0 + sd;
        float4 v = make_float4(BIGV, BIGV, BIGV, BIGV);
        if (s <= 510){
            const int im = imin_of(s), ix = imax_of(s);
            const int i0 = q << 2;
            if (i0 + 0 >= im && i0 + 0 <= ix) v.x = Band[sd*65 + (i0 + 0 - im)];
            if (i0 + 1 >= im && i0 + 1 <= ix) v.y = Band[sd*65 + (i0 + 1 - im)];
            if (i0 + 2 >= im && i0 + 2 <= ix) v.z = Band[sd*65 + (i0 + 2 - im)];
            if (i0 + 3 >= im && i0 + 3 <= ix) v.w = Band[sd*65 + (i0 + 3 - im)];
        }
        Df4[rowbase4 + ((size_t)sd << 6) + q] = v;
    }
}

// ---------------- Kernel B: absolute-i DP, 4 cells/lane, 1 wave/batch ------------
// f32 D stream, v_min3, 6-deep group prefetch (~40-step / ~880cy cover).
__global__ __launch_bounds__(64) void ldtw_dp(const float* __restrict__ Df,
                                              float* __restrict__ out)
{
    const int b = blockIdx.x;
    const int L = threadIdx.x;                        // cells i = 4L..4L+3
    const float4* base = (const float4*)Df + ((size_t)b << 15) + L;  // row stride 64

    float p0, p1, p2, p3, q0, q1, q2, q3;
    float d00 = Df[(size_t)b << 17];                  // D(0,0)
    p0 = (L == 0) ? d00 : BIGV; p1 = BIGV; p2 = BIGV; p3 = BIGV;
    q0 = BIGV; q1 = BIGV; q2 = BIGV; q3 = BIGV;

    // group g covers s = 8g+1 .. 8g+8; clamp keeps tail reads in-bounds-ish
#define LOADG(Bk, g) { \
    const int gg_ = ((g) > 63) ? 63 : (g); \
    const float4* r0_ = base + (size_t)((gg_ << 3) + 1) * 64; \
    const float4* r1_ = r0_ + 256; \
    Bk##0 = r0_[0];   Bk##1 = r0_[64];  Bk##2 = r0_[128]; Bk##3 = r0_[192]; \
    Bk##4 = r1_[0];   Bk##5 = r1_[64];  Bk##6 = r1_[128]; Bk##7 = r1_[192]; }

    // prev1 = p, prev2 = q -> new into q (q becomes prev1)
#define STEP_PQ(V) { \
    float s1_ = dpp_shr1(p3), s2_ = dpp_shr1(q3); \
    float n0 = min3f(s1_, p0, s2_) + (V).x; \
    float n1 = min3f(p0, p1, q0) + (V).y; \
    float n2 = min3f(p1, p2, q1) + (V).z; \
    float n3 = min3f(p2, p3, q2) + (V).w; \
    q0 = n0; q1 = n1; q2 = n2; q3 = n3; }
#define STEP_QP(V) { \
    float s1_ = dpp_shr1(q3), s2_ = dpp_shr1(p3); \
    float n0 = min3f(s1_, q0, s2_) + (V).x; \
    float n1 = min3f(q0, q1, p0) + (V).y; \
    float n2 = min3f(q1, q2, p1) + (V).z; \
    float n3 = min3f(q2, q3, p2) + (V).w; \
    p0 = n0; p1 = n1; p2 = n2; p3 = n3; }

#define GROUP8(Bk) \
    STEP_PQ(Bk##0) STEP_QP(Bk##1) STEP_PQ(Bk##2) STEP_QP(Bk##3) \
    STEP_PQ(Bk##4) STEP_QP(Bk##5) STEP_PQ(Bk##6) STEP_QP(Bk##7)

    float4 A0,A1,A2,A3,A4,A5,A6,A7;
    float4 B0,B1,B2,B3,B4,B5,B6,B7;
    float4 C0,C1,C2,C3,C4,C5,C6,C7;
    float4 E0,E1,E2,E3,E4,E5,E6,E7;
    float4 F0,F1,F2,F3,F4,F5,F6,F7;
    float4 G0,G1,G2,G3,G4,G5,G6,G7;
    LOADG(A, 0) LOADG(B, 1) LOADG(C, 2) LOADG(E, 3) LOADG(F, 4) LOADG(G, 5)
    for (int m = 0; m < 60; m += 6){       // consumes groups 0..59 (s = 1..480)
        GROUP8(A) LOADG(A, m + 6)
        GROUP8(B) LOADG(B, m + 7)
        GROUP8(C) LOADG(C, m + 8)
        GROUP8(E) LOADG(E, m + 9)
        GROUP8(F) LOADG(F, m + 10)
        GROUP8(G) LOADG(G, m + 11)
    }
    GROUP8(A)                               // group 60: s = 481..488
    GROUP8(B)                               // group 61: s = 489..496
    GROUP8(C)                               // group 62: s = 497..504
    STEP_PQ(E0) STEP_QP(E1) STEP_PQ(E2) STEP_QP(E3) STEP_PQ(E4) STEP_QP(E5) // 505..510

    if (L == 63) out[b] = p3;               // dp[510][255]
#undef LOADG
#undef STEP_PQ
#undef STEP_QP
#undef GROUP8
}

// ---------------- Fallback (tiny ws): fused, D on the fly ----------------
__device__ __forceinline__ float cell_d(const float4* __restrict__ Xb,
                                        const float4* __restrict__ Yb,
                                        int i, int j)
{
    const float4* xr = Xb + i*16;
    const float4* yr = Yb + j*16;
    float acc = 0.f;
    #pragma unroll
    for (int k = 0; k < 16; ++k){
        float4 a = xr[k], bb = yr[k];
        float dx = a.x-bb.x, dy = a.y-bb.y, dz = a.z-bb.z, dw = a.w-bb.w;
        acc += dx*dx + dy*dy + dz*dz + dw*dw;
    }
    return acc;
}

__global__ __launch_bounds__(64) void ldtw_fused_fb(const float* __restrict__ X,
                                                    const float* __restrict__ Y,
                                                    float* __restrict__ out)
{
    const int b = blockIdx.x;
    const int l = threadIdx.x;
    const float4* Xb = (const float4*)(X + (size_t)b * NPT * 64);
    const float4* Yb = (const float4*)(Y + (size_t)b * NPT * 64);
    float prev1 = (l == 0) ? cell_d(Xb, Yb, 0, 0) : BIGV;
    float prev2 = BIGV;
    int base1 = 0, base2 = 0;
    for (int s = 1; s <= 510; ++s){
        const int im = imin_of(s);
        const int ix = imax_of(s);
        const int i  = im + l;
        const bool act = (i <= ix);
        const int ic = act ? i : ix;
        const int j  = s - ic;
        float Dv = cell_d(Xb, Yb, ic, j);
        const int d1 = im - base1, d2 = im - base2;
        float sr1 = dpp_shr1(prev1), sl1 = dpp_shl1(prev1);
        float sr2 = dpp_shr1(prev2), sl2 = dpp_shl1(prev2);
        float m1 = d1 ? fminf(prev1, sl1) : fminf(sr1, prev1);
        float vd = (d2 == 0) ? sr2 : ((d2 == 2) ? sl2 : prev2);
        float m3 = fminf(m1, vd);
        float cur = act ? (m3 + Dv) : BIGV;
        prev2 = prev1; base2 = base1;
        prev1 = cur;   base1 = im;
    }
    if (l == 0) out[b] = prev1;
}

extern "C" void kernel_launch(void* const* d_in, const int* in_sizes, int n_in,
                              void* d_out, int out_size, void* d_ws, size_t ws_size,
                              hipStream_t stream)
{
    const float* X = (const float*)d_in[0];
    const float* Y = (const float*)d_in[1];
    float* out = (float*)d_out;
    const int Bn = in_sizes[0] / (NPT * 64);     // = 16
    // Df: Bn * 512 rows * 256 f32 = Bn * 512 KiB; + slack for tail over-read
    const size_t need = (size_t)Bn * 512 * 256 * 4 + 65536;
    if (ws_size >= need){
        float* Df = (float*)d_ws;
        hipLaunchKernelGGL(ldtw_dist, dim3(Bn * 8), dim3(256), 0, stream, X, Y, Df);
        hipLaunchKernelGGL(ldtw_dp,   dim3(Bn),     dim3(64),  0, stream, Df, out);
    } else {
        hipLaunchKernelGGL(ldtw_fused_fb, dim3(Bn), dim3(64), 0, stream, X, Y, out);
    }
}

// Round 7
// 61.207 us; speedup vs baseline: 1.7978x; 1.7978x over previous
//
#include <hip/hip_runtime.h>

#define BIGV 1e9f
#define NPT 256            // N == M == 256

// band: |i-j| <= 51.  i-window on diagonal s:
__device__ __forceinline__ int imin_of(int s){
    int a = s - 255; if (a < 0) a = 0;            // j = s-i <= 255
    int c = s - 50;  c = (c > 0) ? (c >> 1) : 0;  // ceil((s-51)/2)
    return (a > c) ? a : c;
}
__device__ __forceinline__ int imax_of(int s){
    int a = (s < 255) ? s : 255;
    int c = (s + 51) >> 1;                        // floor((s+51)/2)
    return (a < c) ? a : c;
}

// wave-wide shift by 1 with BIG fill (no LDS): lane l <- x[l-1]
__device__ __forceinline__ float dpp_shr1(float x){
    return __int_as_float(__builtin_amdgcn_update_dpp(
        __float_as_int(BIGV), __float_as_int(x), 0x138 /*WAVE_SHR1*/, 0xF, 0xF, false));
}
__device__ __forceinline__ float dpp_shl1(float x){
    return __int_as_float(__builtin_amdgcn_update_dpp(
        __float_as_int(BIGV), __float_as_int(x), 0x130 /*WAVE_SHL1*/, 0xF, 0xF, false));
}

__device__ __forceinline__ float min3f(float a, float b, float c){
    float r;
    asm("v_min3_f32 %0, %1, %2, %3" : "=v"(r) : "v"(a), "v"(b), "v"(c));
    return r;
}

// ---------------- Kernel A: banded distances -> full f32 rows in d_ws ------------
// Df layout: f32, row (b*512 + s) has 256 floats (i = 0..255), BIG outside band.
// Row 511 all-BIG. grid = B*8, block (b,c) owns s in [64c, 64c+63].
// launch_bounds (256,1): 1 block/CU is all we use (128 blocks / 256 CUs), so let
// the allocator have the full 512-VGPR budget -> no spills for the 6x6 tile.
__global__ __launch_bounds__(256, 1) void ldtw_dist(const float* __restrict__ X,
                                                    const float* __restrict__ Y,
                                                    float* __restrict__ Df)
{
    __shared__ float4 Xs[96*17];
    __shared__ float4 Ys[96*17];
    __shared__ float nX[96], nY[96];
    __shared__ float Band[64*65];   // pitch 65
    const int b  = blockIdx.x >> 3;
    const int c  = blockIdx.x & 7;
    const int s0 = c << 6;
    const int s1 = (s0 + 63 > 510) ? 510 : (s0 + 63);
    const int ilo = imin_of(s0), ihi = imax_of(s1);
    const int jlo = s0 - imax_of(s0), jhi = s1 - imin_of(s1);
    const int nx = ihi - ilo + 1, ny = jhi - jlo + 1;   // each <= 96
    const int t = threadIdx.x;
    const float4* Xb = (const float4*)(X + (size_t)b * NPT * 64);
    const float4* Yb = (const float4*)(Y + (size_t)b * NPT * 64);

    for (int idx = t; idx < nx * 16; idx += 256){
        int r = idx >> 4, k = idx & 15;
        Xs[r*17 + k] = Xb[(ilo + r)*16 + k];
    }
    for (int idx = t; idx < ny * 16; idx += 256){
        int r = idx >> 4, k = idx & 15;
        Ys[r*17 + k] = Yb[(jlo + r)*16 + k];
    }
    __syncthreads();

    for (int r = t; r < nx + ny; r += 256){
        const float4* row = (r < nx) ? (Xs + r*17) : (Ys + (r - nx)*17);
        float acc = 0.f;
        #pragma unroll
        for (int k = 0; k < 16; ++k){
            float4 v = row[k];
            acc += v.x*v.x + v.y*v.y + v.z*v.z + v.w*v.w;
        }
        if (r < nx) nX[r] = acc; else nY[r - nx] = acc;
    }
    __syncthreads();

    // phase 1: 6x6 register-tiled dot products over the covering rectangle.
    // Thread (ti,tj) owns rows {ti+16u} x cols {tj+16v}, u,v in [0,6).
    // k-loop unroll bounded to 4 to keep max-live bounded (round-6 spill fix).
    {
        const int ti = t >> 4;       // 0..15
        const int tj = t & 15;       // 0..15
        float acc[6][6];
        #pragma unroll
        for (int u = 0; u < 6; ++u)
            #pragma unroll
            for (int v = 0; v < 6; ++v) acc[u][v] = 0.f;

        #pragma unroll 4
        for (int k = 0; k < 16; ++k){
            float4 xa[6], ya[6];
            #pragma unroll
            for (int u = 0; u < 6; ++u){
                xa[u] = Xs[(ti + u*16)*17 + k];
                ya[u] = Ys[(tj + u*16)*17 + k];
            }
            #pragma unroll
            for (int u = 0; u < 6; ++u)
                #pragma unroll
                for (int v = 0; v < 6; ++v)
                    acc[u][v] += xa[u].x*ya[v].x + xa[u].y*ya[v].y
                               + xa[u].z*ya[v].z + xa[u].w*ya[v].w;
        }

        #pragma unroll
        for (int u = 0; u < 6; ++u){
            #pragma unroll
            for (int v = 0; v < 6; ++v){
                const int iloc = ti + u*16, jloc = tj + v*16;
                const int i = ilo + iloc, j = jlo + jloc;
                const int s = i + j;
                if (s >= s0 && s <= s1){
                    const int im = imin_of(s), ix = imax_of(s);
                    if (i >= im && i <= ix)
                        Band[(s - s0)*65 + (i - im)] =
                            nX[iloc] + nY[jloc] - 2.f*acc[u][v];
                }
            }
        }
    }
    __syncthreads();

    // phase 2: emit full 256-wide f32 rows (BIG outside band), coalesced float4
    float4* Df4 = (float4*)Df;
    const size_t rowbase4 = ((size_t)(b * 512 + s0)) << 6;   // float4 units, 64/row
    for (int slot = t; slot < 64*64; slot += 256){
        const int sd = slot >> 6, q = slot & 63;
        const int s  = s0 + sd;
        float4 v = make_float4(BIGV, BIGV, BIGV, BIGV);
        if (s <= 510){
            const int im = imin_of(s), ix = imax_of(s);
            const int i0 = q << 2;
            if (i0 + 0 >= im && i0 + 0 <= ix) v.x = Band[sd*65 + (i0 + 0 - im)];
            if (i0 + 1 >= im && i0 + 1 <= ix) v.y = Band[sd*65 + (i0 + 1 - im)];
            if (i0 + 2 >= im && i0 + 2 <= ix) v.z = Band[sd*65 + (i0 + 2 - im)];
            if (i0 + 3 >= im && i0 + 3 <= ix) v.w = Band[sd*65 + (i0 + 3 - im)];
        }
        Df4[rowbase4 + ((size_t)sd << 6) + q] = v;
    }
}

// ---------------- Kernel B: absolute-i DP, 4 cells/lane, 1 wave/batch ------------
// f32 D stream, v_min3, 6-deep group prefetch (~40-step / ~880cy cover).
__global__ __launch_bounds__(64) void ldtw_dp(const float* __restrict__ Df,
                                              float* __restrict__ out)
{
    const int b = blockIdx.x;
    const int L = threadIdx.x;                        // cells i = 4L..4L+3
    const float4* base = (const float4*)Df + ((size_t)b << 15) + L;  // row stride 64

    float p0, p1, p2, p3, q0, q1, q2, q3;
    float d00 = Df[(size_t)b << 17];                  // D(0,0)
    p0 = (L == 0) ? d00 : BIGV; p1 = BIGV; p2 = BIGV; p3 = BIGV;
    q0 = BIGV; q1 = BIGV; q2 = BIGV; q3 = BIGV;

    // group g covers s = 8g+1 .. 8g+8; clamp keeps tail reads near-bounds
#define LOADG(Bk, g) { \
    const int gg_ = ((g) > 63) ? 63 : (g); \
    const float4* r0_ = base + (size_t)((gg_ << 3) + 1) * 64; \
    const float4* r1_ = r0_ + 256; \
    Bk##0 = r0_[0];   Bk##1 = r0_[64];  Bk##2 = r0_[128]; Bk##3 = r0_[192]; \
    Bk##4 = r1_[0];   Bk##5 = r1_[64];  Bk##6 = r1_[128]; Bk##7 = r1_[192]; }

    // prev1 = p, prev2 = q -> new into q (q becomes prev1)
#define STEP_PQ(V) { \
    float s1_ = dpp_shr1(p3), s2_ = dpp_shr1(q3); \
    float n0 = min3f(s1_, p0, s2_) + (V).x; \
    float n1 = min3f(p0, p1, q0) + (V).y; \
    float n2 = min3f(p1, p2, q1) + (V).z; \
    float n3 = min3f(p2, p3, q2) + (V).w; \
    q0 = n0; q1 = n1; q2 = n2; q3 = n3; }
#define STEP_QP(V) { \
    float s1_ = dpp_shr1(q3), s2_ = dpp_shr1(p3); \
    float n0 = min3f(s1_, q0, s2_) + (V).x; \
    float n1 = min3f(q0, q1, p0) + (V).y; \
    float n2 = min3f(q1, q2, p1) + (V).z; \
    float n3 = min3f(q2, q3, p2) + (V).w; \
    p0 = n0; p1 = n1; p2 = n2; p3 = n3; }

#define GROUP8(Bk) \
    STEP_PQ(Bk##0) STEP_QP(Bk##1) STEP_PQ(Bk##2) STEP_QP(Bk##3) \
    STEP_PQ(Bk##4) STEP_QP(Bk##5) STEP_PQ(Bk##6) STEP_QP(Bk##7)

    float4 A0,A1,A2,A3,A4,A5,A6,A7;
    float4 B0,B1,B2,B3,B4,B5,B6,B7;
    float4 C0,C1,C2,C3,C4,C5,C6,C7;
    float4 E0,E1,E2,E3,E4,E5,E6,E7;
    float4 F0,F1,F2,F3,F4,F5,F6,F7;
    float4 G0,G1,G2,G3,G4,G5,G6,G7;
    LOADG(A, 0) LOADG(B, 1) LOADG(C, 2) LOADG(E, 3) LOADG(F, 4) LOADG(G, 5)
    for (int m = 0; m < 60; m += 6){       // consumes groups 0..59 (s = 1..480)
        GROUP8(A) LOADG(A, m + 6)
        GROUP8(B) LOADG(B, m + 7)
        GROUP8(C) LOADG(C, m + 8)
        GROUP8(E) LOADG(E, m + 9)
        GROUP8(F) LOADG(F, m + 10)
        GROUP8(G) LOADG(G, m + 11)
    }
    GROUP8(A)                               // group 60: s = 481..488
    GROUP8(B)                               // group 61: s = 489..496
    GROUP8(C)                               // group 62: s = 497..504
    STEP_PQ(E0) STEP_QP(E1) STEP_PQ(E2) STEP_QP(E3) STEP_PQ(E4) STEP_QP(E5) // 505..510

    if (L == 63) out[b] = p3;               // dp[510][255]
#undef LOADG
#undef STEP_PQ
#undef STEP_QP
#undef GROUP8
}

// ---------------- Fallback (tiny ws): fused, D on the fly ----------------
__device__ __forceinline__ float cell_d(const float4* __restrict__ Xb,
                                        const float4* __restrict__ Yb,
                                        int i, int j)
{
    const float4* xr = Xb + i*16;
    const float4* yr = Yb + j*16;
    float acc = 0.f;
    #pragma unroll
    for (int k = 0; k < 16; ++k){
        float4 a = xr[k], bb = yr[k];
        float dx = a.x-bb.x, dy = a.y-bb.y, dz = a.z-bb.z, dw = a.w-bb.w;
        acc += dx*dx + dy*dy + dz*dz + dw*dw;
    }
    return acc;
}

__global__ __launch_bounds__(64) void ldtw_fused_fb(const float* __restrict__ X,
                                                    const float* __restrict__ Y,
                                                    float* __restrict__ out)
{
    const int b = blockIdx.x;
    const int l = threadIdx.x;
    const float4* Xb = (const float4*)(X + (size_t)b * NPT * 64);
    const float4* Yb = (const float4*)(Y + (size_t)b * NPT * 64);
    float prev1 = (l == 0) ? cell_d(Xb, Yb, 0, 0) : BIGV;
    float prev2 = BIGV;
    int base1 = 0, base2 = 0;
    for (int s = 1; s <= 510; ++s){
        const int im = imin_of(s);
        const int ix = imax_of(s);
        const int i  = im + l;
        const bool act = (i <= ix);
        const int ic = act ? i : ix;
        const int j  = s - ic;
        float Dv = cell_d(Xb, Yb, ic, j);
        const int d1 = im - base1, d2 = im - base2;
        float sr1 = dpp_shr1(prev1), sl1 = dpp_shl1(prev1);
        float sr2 = dpp_shr1(prev2), sl2 = dpp_shl1(prev2);
        float m1 = d1 ? fminf(prev1, sl1) : fminf(sr1, prev1);
        float vd = (d2 == 0) ? sr2 : ((d2 == 2) ? sl2 : prev2);
        float m3 = fminf(m1, vd);
        float cur = act ? (m3 + Dv) : BIGV;
        prev2 = prev1; base2 = base1;
        prev1 = cur;   base1 = im;
    }
    if (l == 0) out[b] = prev1;
}

extern "C" void kernel_launch(void* const* d_in, const int* in_sizes, int n_in,
                              void* d_out, int out_size, void* d_ws, size_t ws_size,
                              hipStream_t stream)
{
    const float* X = (const float*)d_in[0];
    const float* Y = (const float*)d_in[1];
    float* out = (float*)d_out;
    const int Bn = in_sizes[0] / (NPT * 64);     // = 16
    // Df: Bn * 512 rows * 256 f32 = Bn * 512 KiB; + slack for tail over-read
    const size_t need = (size_t)Bn * 512 * 256 * 4 + 65536;
    if (ws_size >= need){
        float* Df = (float*)d_ws;
        hipLaunchKernelGGL(ldtw_dist, dim3(Bn * 8), dim3(256), 0, stream, X, Y, Df);
        hipLaunchKernelGGL(ldtw_dp,   dim3(Bn),     dim3(64),  0, stream, Df, out);
    } else {
        hipLaunchKernelGGL(ldtw_fused_fb, dim3(Bn), dim3(64), 0, stream, X, Y, out);
    }
}

// Round 8
// 32.766 us; speedup vs baseline: 3.3582x; 1.8680x over previous
//
#include <hip/hip_runtime.h>

#define BIGV 1e9f
#define NPT 256            // N == M == 256

// band: |i-j| <= 51.  i-window on diagonal s:
__device__ __forceinline__ int imin_of(int s){
    int a = s - 255; if (a < 0) a = 0;            // j = s-i <= 255
    int c = s - 50;  c = (c > 0) ? (c >> 1) : 0;  // ceil((s-51)/2)
    return (a > c) ? a : c;
}
__device__ __forceinline__ int imax_of(int s){
    int a = (s < 255) ? s : 255;
    int c = (s + 51) >> 1;                        // floor((s+51)/2)
    return (a < c) ? a : c;
}

// wave-wide shift by 1 with BIG fill (no LDS): lane l <- x[l-1]
__device__ __forceinline__ float dpp_shr1(float x){
    return __int_as_float(__builtin_amdgcn_update_dpp(
        __float_as_int(BIGV), __float_as_int(x), 0x138 /*WAVE_SHR1*/, 0xF, 0xF, false));
}
__device__ __forceinline__ float dpp_shl1(float x){
    return __int_as_float(__builtin_amdgcn_update_dpp(
        __float_as_int(BIGV), __float_as_int(x), 0x130 /*WAVE_SHL1*/, 0xF, 0xF, false));
}

__device__ __forceinline__ float min3f(float a, float b, float c){
    float r;
    asm("v_min3_f32 %0, %1, %2, %3" : "=v"(r) : "v"(a), "v"(b), "v"(c));
    return r;
}

// ---------------- Kernel A: banded distances -> full f32 rows in d_ws ------------
// Df layout: f32, row (b*512 + s) has 256 floats (i = 0..255), BIG outside band.
// grid = 256 blocks: batch = idx & 15, chunk = idx >> 4 (32 diagonals each).
// batch b's blocks all have blockIdx%8 == b%8 -> same XCD as dp's block b
// (round-robin dispatch heuristic; correctness does not depend on it).
__global__ __launch_bounds__(256, 1) void ldtw_dist(const float* __restrict__ X,
                                                    const float* __restrict__ Y,
                                                    float* __restrict__ Df)
{
    __shared__ float4 Xs[80*17];
    __shared__ float4 Ys[80*17];
    __shared__ float nX[80], nY[80];
    __shared__ float Band[32*65];   // pitch 65
    const int b  = blockIdx.x & 15;
    const int c  = blockIdx.x >> 4;       // 0..15, 32 diagonals each
    const int s0 = c << 5;
    const int s1 = (s0 + 31 > 510) ? 510 : (s0 + 31);
    const int ilo = imin_of(s0), ihi = imax_of(s1);
    const int jlo = s0 - imax_of(s0), jhi = s1 - imin_of(s1);
    const int nx = ihi - ilo + 1, ny = jhi - jlo + 1;   // each <= 68
    const int t = threadIdx.x;
    const float4* Xb = (const float4*)(X + (size_t)b * NPT * 64);
    const float4* Yb = (const float4*)(Y + (size_t)b * NPT * 64);

    for (int idx = t; idx < nx * 16; idx += 256){
        int r = idx >> 4, k = idx & 15;
        Xs[r*17 + k] = Xb[(ilo + r)*16 + k];
    }
    for (int idx = t; idx < ny * 16; idx += 256){
        int r = idx >> 4, k = idx & 15;
        Ys[r*17 + k] = Yb[(jlo + r)*16 + k];
    }
    __syncthreads();

    for (int r = t; r < nx + ny; r += 256){
        const float4* row = (r < nx) ? (Xs + r*17) : (Ys + (r - nx)*17);
        float acc = 0.f;
        #pragma unroll
        for (int k = 0; k < 16; ++k){
            float4 v = row[k];
            acc += v.x*v.x + v.y*v.y + v.z*v.z + v.w*v.w;
        }
        if (r < nx) nX[r] = acc; else nY[r - nx] = acc;
    }
    __syncthreads();

    // phase 1: 5x5 register-tiled dot products over the covering rectangle
    // (rows ti+16u, cols tj+16v; out-of-band cells discarded by the guard).
    {
        const int ti = t >> 4;       // 0..15
        const int tj = t & 15;       // 0..15
        float acc[5][5];
        #pragma unroll
        for (int u = 0; u < 5; ++u)
            #pragma unroll
            for (int v = 0; v < 5; ++v) acc[u][v] = 0.f;

        #pragma unroll 4
        for (int k = 0; k < 16; ++k){
            float4 xa[5], ya[5];
            #pragma unroll
            for (int u = 0; u < 5; ++u){
                xa[u] = Xs[(ti + u*16)*17 + k];
                ya[u] = Ys[(tj + u*16)*17 + k];
            }
            #pragma unroll
            for (int u = 0; u < 5; ++u)
                #pragma unroll
                for (int v = 0; v < 5; ++v)
                    acc[u][v] += xa[u].x*ya[v].x + xa[u].y*ya[v].y
                               + xa[u].z*ya[v].z + xa[u].w*ya[v].w;
        }

        #pragma unroll
        for (int u = 0; u < 5; ++u){
            #pragma unroll
            for (int v = 0; v < 5; ++v){
                const int iloc = ti + u*16, jloc = tj + v*16;
                const int i = ilo + iloc, j = jlo + jloc;
                const int s = i + j;
                if (s >= s0 && s <= s1){
                    const int im = imin_of(s), ix = imax_of(s);
                    if (i >= im && i <= ix)
                        Band[(s - s0)*65 + (i - im)] =
                            nX[iloc] + nY[jloc] - 2.f*acc[u][v];
                }
            }
        }
    }
    __syncthreads();

    // phase 2: emit full 256-wide f32 rows (BIG outside band), coalesced float4
    float4* Df4 = (float4*)Df;
    const size_t rowbase4 = ((size_t)(b * 512 + s0)) << 6;   // float4 units, 64/row
    for (int slot = t; slot < 32*64; slot += 256){
        const int sd = slot >> 6, q = slot & 63;
        const int s  = s0 + sd;
        float4 v = make_float4(BIGV, BIGV, BIGV, BIGV);
        if (s <= 510){
            const int im = imin_of(s), ix = imax_of(s);
            const int i0 = q << 2;
            if (i0 + 0 >= im && i0 + 0 <= ix) v.x = Band[sd*65 + (i0 + 0 - im)];
            if (i0 + 1 >= im && i0 + 1 <= ix) v.y = Band[sd*65 + (i0 + 1 - im)];
            if (i0 + 2 >= im && i0 + 2 <= ix) v.z = Band[sd*65 + (i0 + 2 - im)];
            if (i0 + 3 >= im && i0 + 3 <= ix) v.w = Band[sd*65 + (i0 + 3 - im)];
        }
        Df4[rowbase4 + ((size_t)sd << 6) + q] = v;
    }
}

// ---------------- Kernel B: absolute-i DP, 4 cells/lane, 1 wave/batch ------------
// f32 D stream, v_min3, 4-deep group prefetch; block b reads L2-local Df.
__global__ __launch_bounds__(64) void ldtw_dp(const float* __restrict__ Df,
                                              float* __restrict__ out)
{
    const int b = blockIdx.x;
    const int L = threadIdx.x;                        // cells i = 4L..4L+3
    const float4* base = (const float4*)Df + ((size_t)b << 15) + L;  // row stride 64

    float p0, p1, p2, p3, q0, q1, q2, q3;
    float d00 = Df[(size_t)b << 17];                  // D(0,0)
    p0 = (L == 0) ? d00 : BIGV; p1 = BIGV; p2 = BIGV; p3 = BIGV;
    q0 = BIGV; q1 = BIGV; q2 = BIGV; q3 = BIGV;

    // group g covers s = 8g+1 .. 8g+8; two bases keep imm offsets within 4KB
#define LOADG(Bk, g) { \
    const float4* r0_ = base + (size_t)(((g) << 3) + 1) * 64; \
    const float4* r1_ = r0_ + 256; \
    Bk##0 = r0_[0];   Bk##1 = r0_[64];  Bk##2 = r0_[128]; Bk##3 = r0_[192]; \
    Bk##4 = r1_[0];   Bk##5 = r1_[64];  Bk##6 = r1_[128]; Bk##7 = r1_[192]; }

    // prev1 = p, prev2 = q -> new into q (q becomes prev1)
#define STEP_PQ(V) { \
    float s1_ = dpp_shr1(p3), s2_ = dpp_shr1(q3); \
    float n0 = min3f(s1_, p0, s2_) + (V).x; \
    float n1 = min3f(p0, p1, q0) + (V).y; \
    float n2 = min3f(p1, p2, q1) + (V).z; \
    float n3 = min3f(p2, p3, q2) + (V).w; \
    q0 = n0; q1 = n1; q2 = n2; q3 = n3; }
#define STEP_QP(V) { \
    float s1_ = dpp_shr1(q3), s2_ = dpp_shr1(p3); \
    float n0 = min3f(s1_, q0, s2_) + (V).x; \
    float n1 = min3f(q0, q1, p0) + (V).y; \
    float n2 = min3f(q1, q2, p1) + (V).z; \
    float n3 = min3f(q2, q3, p2) + (V).w; \
    p0 = n0; p1 = n1; p2 = n2; p3 = n3; }

#define GROUP8(Bk) \
    STEP_PQ(Bk##0) STEP_QP(Bk##1) STEP_PQ(Bk##2) STEP_QP(Bk##3) \
    STEP_PQ(Bk##4) STEP_QP(Bk##5) STEP_PQ(Bk##6) STEP_QP(Bk##7)

    float4 A0,A1,A2,A3,A4,A5,A6,A7;
    float4 B0,B1,B2,B3,B4,B5,B6,B7;
    float4 C0,C1,C2,C3,C4,C5,C6,C7;
    float4 E0,E1,E2,E3,E4,E5,E6,E7;
    LOADG(A, 0) LOADG(B, 1) LOADG(C, 2) LOADG(E, 3)
    for (int m = 0; m < 60; m += 4){       // consumes groups 0..59 (s = 1..480)
        GROUP8(A) LOADG(A, m + 4)
        GROUP8(B) LOADG(B, m + 5)
        GROUP8(C) LOADG(C, m + 6)
        GROUP8(E) LOADG(E, m + 7)
    }
    GROUP8(A)                               // group 60: s = 481..488
    GROUP8(B)                               // group 61: s = 489..496
    GROUP8(C)                               // group 62: s = 497..504
    STEP_PQ(E0) STEP_QP(E1) STEP_PQ(E2) STEP_QP(E3) STEP_PQ(E4) STEP_QP(E5) // 505..510

    if (L == 63) out[b] = p3;               // dp[510][255]
#undef LOADG
#undef STEP_PQ
#undef STEP_QP
#undef GROUP8
}

// ---------------- Fallback (tiny ws): fused, D on the fly ----------------
__device__ __forceinline__ float cell_d(const float4* __restrict__ Xb,
                                        const float4* __restrict__ Yb,
                                        int i, int j)
{
    const float4* xr = Xb + i*16;
    const float4* yr = Yb + j*16;
    float acc = 0.f;
    #pragma unroll
    for (int k = 0; k < 16; ++k){
        float4 a = xr[k], bb = yr[k];
        float dx = a.x-bb.x, dy = a.y-bb.y, dz = a.z-bb.z, dw = a.w-bb.w;
        acc += dx*dx + dy*dy + dz*dz + dw*dw;
    }
    return acc;
}

__global__ __launch_bounds__(64) void ldtw_fused_fb(const float* __restrict__ X,
                                                    const float* __restrict__ Y,
                                                    float* __restrict__ out)
{
    const int b = blockIdx.x;
    const int l = threadIdx.x;
    const float4* Xb = (const float4*)(X + (size_t)b * NPT * 64);
    const float4* Yb = (const float4*)(Y + (size_t)b * NPT * 64);
    float prev1 = (l == 0) ? cell_d(Xb, Yb, 0, 0) : BIGV;
    float prev2 = BIGV;
    int base1 = 0, base2 = 0;
    for (int s = 1; s <= 510; ++s){
        const int im = imin_of(s);
        const int ix = imax_of(s);
        const int i  = im + l;
        const bool act = (i <= ix);
        const int ic = act ? i : ix;
        const int j  = s - ic;
        float Dv = cell_d(Xb, Yb, ic, j);
        const int d1 = im - base1, d2 = im - base2;
        float sr1 = dpp_shr1(prev1), sl1 = dpp_shl1(prev1);
        float sr2 = dpp_shr1(prev2), sl2 = dpp_shl1(prev2);
        float m1 = d1 ? fminf(prev1, sl1) : fminf(sr1, prev1);
        float vd = (d2 == 0) ? sr2 : ((d2 == 2) ? sl2 : prev2);
        float m3 = fminf(m1, vd);
        float cur = act ? (m3 + Dv) : BIGV;
        prev2 = prev1; base2 = base1;
        prev1 = cur;   base1 = im;
    }
    if (l == 0) out[b] = prev1;
}

extern "C" void kernel_launch(void* const* d_in, const int* in_sizes, int n_in,
                              void* d_out, int out_size, void* d_ws, size_t ws_size,
                              hipStream_t stream)
{
    const float* X = (const float*)d_in[0];
    const float* Y = (const float*)d_in[1];
    float* out = (float*)d_out;
    const int Bn = in_sizes[0] / (NPT * 64);     // = 16
    // Df: Bn * 512 rows * 256 f32 = Bn * 512 KiB; + slack for tail over-read
    const size_t need = (size_t)Bn * 512 * 256 * 4 + 65536;
    if (ws_size >= need && Bn == 16){
        float* Df = (float*)d_ws;
        hipLaunchKernelGGL(ldtw_dist, dim3(256),  dim3(256), 0, stream, X, Y, Df);
        hipLaunchKernelGGL(ldtw_dp,   dim3(Bn),   dim3(64),  0, stream, Df, out);
    } else {
        hipLaunchKernelGGL(ldtw_fused_fb, dim3(Bn), dim3(64), 0, stream, X, Y, out);
    }
}